// Round 16
// baseline (346.789 us; speedup 1.0000x reference)
//
#include <hip/hip_runtime.h>
#include <stdint.h>

#define D_DIM 4096
#define O_DIM 4096
#define M_DIM 8192
#define BK 32
#define NKT 128  // D_DIM / BK

typedef __attribute__((ext_vector_type(4))) float f32x4;
typedef __attribute__((ext_vector_type(8))) __bf16 bf16x8;
typedef __attribute__((ext_vector_type(8))) unsigned short u16x8;

__device__ __forceinline__ unsigned short f32_to_bf16_bits(float f) {
    union { float f; uint32_t u; } v; v.f = f;
    return (unsigned short)((v.u + 0x7FFFu + ((v.u >> 16) & 1u)) >> 16);
}

__device__ __forceinline__ float dot4(f32x4 a, f32x4 b) {
    return fmaf(a.x, b.x, fmaf(a.y, b.y, fmaf(a.z, b.z, a.w * b.w)));
}

// swizzle involution on byte offsets within a 16 KiB [256 rows][64 B] tile:
// XOR bits 4-6 with bits 7-9. Conflict-free for the 16x16 fragment pattern
// (verified 0 conflicts rounds 3-15; 32x32 port conflicted and was reverted).
__device__ __forceinline__ int swz(int b) { return b ^ (((b >> 7) & 7) << 4); }

// ---------------- Kernel 1: f32 -> bf16 convert (W_base) ----------------
__global__ __launch_bounds__(256) void convert_bf16_kernel(const float* __restrict__ src,
                                                           unsigned short* __restrict__ dst,
                                                           int n4) {
    int stride = gridDim.x * blockDim.x;
    for (int i = blockIdx.x * blockDim.x + threadIdx.x; i < n4; i += stride) {
        f32x4 v = ((const f32x4*)src)[i];
        ushort4 o;
        o.x = f32_to_bf16_bits(v.x);
        o.y = f32_to_bf16_bits(v.y);
        o.z = f32_to_bf16_bits(v.z);
        o.w = f32_to_bf16_bits(v.w);
        ((ushort4*)dst)[i] = o;
    }
}

// ---------------- Kernel 2a: partial Y + fused x->bf16 convert (round-13, kept) ---------
__global__ __launch_bounds__(256) void partial_mixed_kernel(const float* __restrict__ x,
                                                            const float* __restrict__ A_w,
                                                            const float* __restrict__ router_w,
                                                            unsigned short* __restrict__ xbf,
                                                            float* __restrict__ ypart) {
    __shared__ __align__(16) float Xc[32][132];
    __shared__ __align__(16) float Wc[24][132];

    const int tid = threadIdx.x;
    const int t0 = blockIdx.x * 32;
    const int d0 = blockIdx.y * 512;

    const int slot = tid & 63;
    const int q = tid >> 6;
    const int tg4 = slot >> 3;
    const int og = slot & 7;

    float acc[4][3];
    #pragma unroll
    for (int ti = 0; ti < 4; ++ti)
        #pragma unroll
        for (int wi = 0; wi < 3; ++wi) acc[ti][wi] = 0.f;

    for (int sub = 0; sub < 4; ++sub) {
        const int dbase = d0 + sub * 128;
        __syncthreads();
        #pragma unroll
        for (int i = 0; i < 4; ++i) {
            int idx = i * 256 + tid;
            int t = idx >> 5, dq = idx & 31;
            f32x4 v = *(const f32x4*)&x[(size_t)(t0 + t) * D_DIM + dbase + dq * 4];
            *(f32x4*)&Xc[t][dq * 4] = v;
            ushort4 o;
            o.x = f32_to_bf16_bits(v.x);
            o.y = f32_to_bf16_bits(v.y);
            o.z = f32_to_bf16_bits(v.z);
            o.w = f32_to_bf16_bits(v.w);
            *(ushort4*)&xbf[(size_t)(t0 + t) * D_DIM + dbase + dq * 4] = o;
        }
        #pragma unroll
        for (int i = 0; i < 3; ++i) {
            int idx = i * 256 + tid;
            int r = idx >> 5, dq = idx & 31;
            const float* src = (r < 16) ? (A_w + (size_t)r * D_DIM)
                                        : (router_w + (size_t)(r - 16) * D_DIM);
            *(f32x4*)&Wc[r][dq * 4] = *(const f32x4*)&src[dbase + dq * 4];
        }
        __syncthreads();
        #pragma unroll
        for (int dqi = 0; dqi < 8; ++dqi) {
            const int dq = q * 8 + dqi;
            f32x4 w0 = *(const f32x4*)&Wc[og * 3 + 0][dq * 4];
            f32x4 w1 = *(const f32x4*)&Wc[og * 3 + 1][dq * 4];
            f32x4 w2 = *(const f32x4*)&Wc[og * 3 + 2][dq * 4];
            #pragma unroll
            for (int ti = 0; ti < 4; ++ti) {
                f32x4 xv = *(const f32x4*)&Xc[tg4 * 4 + ti][dq * 4];
                acc[ti][0] += dot4(xv, w0);
                acc[ti][1] += dot4(xv, w1);
                acc[ti][2] += dot4(xv, w2);
            }
        }
    }

    __syncthreads();
    float* red = &Xc[0][0];
    #pragma unroll
    for (int ti = 0; ti < 4; ++ti)
        #pragma unroll
        for (int wi = 0; wi < 3; ++wi)
            red[(slot * 4 + q) * 12 + ti * 3 + wi] = acc[ti][wi];
    __syncthreads();
    #pragma unroll
    for (int k = 0; k < 3; ++k) {
        const int flat = tid * 3 + k;
        const int t = flat / 24, j = flat % 24;
        const int s = ((t >> 2) << 3) | (j / 3);
        const int ti = t & 3, wi = j % 3;
        float v = 0.f;
        #pragma unroll
        for (int qq = 0; qq < 4; ++qq) v += red[(s * 4 + qq) * 12 + ti * 3 + wi];
        ypart[(((size_t)blockIdx.y * 256 + blockIdx.x) * 32 + t) * 24 + j] = v;
    }
}

// ---------------- Kernel 2b: finalize (blocks 0-63) + bwbf convert (blocks 64-95) --------
__global__ __launch_bounds__(128) void fin_kernel(const float* __restrict__ ypart,
                                                  const float* __restrict__ cores,
                                                  const float* __restrict__ Bw,
                                                  unsigned short* __restrict__ mixbf,
                                                  unsigned short* __restrict__ bwbf) {
    const int tid = threadIdx.x;

    if (blockIdx.x >= 64) {
        const int o = (blockIdx.x - 64) * 128 + tid;
        ushort4* dst = (ushort4*)&bwbf[(size_t)o * 32];
        #pragma unroll
        for (int g = 0; g < 4; ++g) {
            f32x4 v = *(const f32x4*)&Bw[(size_t)o * 16 + g * 4];
            ushort4 u;
            u.x = f32_to_bf16_bits(v.x);
            u.y = f32_to_bf16_bits(v.y);
            u.z = f32_to_bf16_bits(v.z);
            u.w = f32_to_bf16_bits(v.w);
            dst[g] = u;
        }
        const ushort4 z = {0, 0, 0, 0};
        #pragma unroll
        for (int g = 4; g < 8; ++g) dst[g] = z;
        return;
    }

    __shared__ __align__(16) float Cs[2048];
    #pragma unroll
    for (int i = 0; i < 4; ++i) {
        int idx = i * 128 + tid;
        ((f32x4*)Cs)[idx] = ((const f32x4*)cores)[idx];
    }
    __syncthreads();

    const int tok = blockIdx.x * 128 + tid;
    const int tile = tok >> 5, t = tok & 31;

    float y[24];
    #pragma unroll
    for (int j = 0; j < 24; ++j) y[j] = 0.f;
    for (int ds = 0; ds < 8; ++ds) {
        const float* src = ypart + (((size_t)ds * 256 + tile) * 32 + t) * 24;
        #pragma unroll
        for (int j = 0; j < 24; ++j) y[j] += src[j];
    }

    float mx = y[16];
    #pragma unroll
    for (int e = 1; e < 8; ++e) mx = fmaxf(mx, y[16 + e]);
    float p[8], psum = 0.f;
    #pragma unroll
    for (int e = 0; e < 8; ++e) { p[e] = __expf(y[16 + e] - mx); psum += p[e]; }
    const float inv = 1.0f / psum;

    float outq[16];
    #pragma unroll
    for (int q = 0; q < 16; ++q) outq[q] = 0.f;
    for (int e = 0; e < 8; ++e) {
        const float pe = p[e] * inv;
        #pragma unroll
        for (int r = 0; r < 16; ++r) {
            const float ar = y[r] * pe;
            #pragma unroll
            for (int q = 0; q < 16; ++q)
                outq[q] = fmaf(ar, Cs[(e * 16 + r) * 16 + q], outq[q]);
        }
    }
    ushort4* dst = (ushort4*)&mixbf[(size_t)tok * 32];
    #pragma unroll
    for (int g = 0; g < 4; ++g) {
        ushort4 u;
        u.x = f32_to_bf16_bits(2.0f * outq[g * 4 + 0]);
        u.y = f32_to_bf16_bits(2.0f * outq[g * 4 + 1]);
        u.z = f32_to_bf16_bits(2.0f * outq[g * 4 + 2]);
        u.w = f32_to_bf16_bits(2.0f * outq[g * 4 + 3]);
        dst[g] = u;
    }
    const ushort4 z = {0, 0, 0, 0};
    #pragma unroll
    for (int g = 4; g < 8; ++g) dst[g] = z;
}

// ---------------- Kernel 3: 256x256-tile GEMM, round-16: RING-2 LDS (64 KiB) ------------
// Round-15 discovery: the 128 KiB ring-4 allowed only 1 block/CU (LDS_Block_Size
// counter) — barrier/vmcnt stalls had no co-resident block to hide behind (MfmaUtil
// stuck ~51.5%). Ring-2 halves LDS -> 2 blocks/CU; the matrix pipe can serve the other
// block during this block's sync stalls. Pipeline depth drops 3->1 but a K-tile
// (~2278 cyc) >> HBM latency (~900): kt=j+1's loads (issued at iter-j start) are
// drained by a cheap vmcnt(0) at iter-j end. Full drain per iter => NO tail peel, no
// counted-vmcnt accounting — strictly simpler sync, race-free by construction
// (buf j&1 is re-staged only by iter j+1's issues, which follow iter j's drained
// barrier). Frags/swizzle/lora-fold/epilogue unchanged from the proven r15 kernel.
__global__ __launch_bounds__(512, 2) void gemm_kernel(const unsigned short* __restrict__ xbf,
                                                      const unsigned short* __restrict__ wbf,
                                                      const float* __restrict__ bias,
                                                      const unsigned short* __restrict__ mixbf,
                                                      const unsigned short* __restrict__ bwbf,
                                                      float* __restrict__ out) {
    __shared__ __align__(16) unsigned short lds[2][2][256 * 32];  // 64 KiB -> 2 blocks/CU

    const int bid = blockIdx.x;
    const int xcd = bid & 7;
    const int lid = bid >> 3;                 // 0..63
    const int tm = (lid >> 4) * 8 + xcd;      // 0..31
    const int tn = lid & 15;                  // 0..15
    const int m0 = tm * 256, n0 = tn * 256;

    const int tid = threadIdx.x;
    const int wave = tid >> 6, lane = tid & 63;
    const int wr = wave >> 2, wcn = wave & 3;  // 2x4 wave grid

    int aoff[2], boff[2], mmoff[2], mboff[2];
    #pragma unroll
    for (int u = 0; u < 2; ++u) {
        int c = u * 512 + tid;
        int g = swz(c * 16);
        int grow = g >> 6, gc8 = (g >> 4) & 3;
        aoff[u] = (m0 + grow) * D_DIM + gc8 * 8;
        boff[u] = (n0 + grow) * D_DIM + gc8 * 8;
        mmoff[u] = (m0 + grow) * 32 + gc8 * 8;
        mboff[u] = (n0 + grow) * 32 + gc8 * 8;
    }

    const int tA = lane & 15, kq = lane >> 4;
    int aRd[8], bRd[4];
    #pragma unroll
    for (int mi = 0; mi < 8; ++mi)
        aRd[mi] = swz((wr * 128 + mi * 16 + tA) * 64 + kq * 16);
    #pragma unroll
    for (int ni = 0; ni < 4; ++ni)
        bRd[ni] = swz((wcn * 64 + ni * 16 + tA) * 64 + kq * 16);

    f32x4 acc[8][4];
    const f32x4 fz = {0.f, 0.f, 0.f, 0.f};
    #pragma unroll
    for (int mi = 0; mi < 8; ++mi)
        #pragma unroll
        for (int ni = 0; ni < 4; ++ni) acc[mi][ni] = fz;

#define STAGE_UNIT(sb, kt, u, isA)                                                        \
    do {                                                                                  \
        const unsigned short* gsrc =                                                      \
            (isA) ? (xbf + aoff[u] + (kt)*BK) : (wbf + boff[u] + (kt)*BK);                \
        __builtin_amdgcn_global_load_lds(                                                 \
            (const __attribute__((address_space(1))) void*)gsrc,                          \
            (__attribute__((address_space(3))) void*)(&lds[sb][(isA) ? 0 : 1]             \
                                                         [((u)*512 + wave * 64) * 8]),    \
            16, 0, 0);                                                                    \
    } while (0)

#define STAGE_MIX(u, isA)                                                                 \
    do {                                                                                  \
        const unsigned short* gsrc = (isA) ? (mixbf + mmoff[u]) : (bwbf + mboff[u]);      \
        __builtin_amdgcn_global_load_lds(                                                 \
            (const __attribute__((address_space(1))) void*)gsrc,                          \
            (__attribute__((address_space(3))) void*)(&lds[0][(isA) ? 0 : 1]              \
                                                         [((u)*512 + wave * 64) * 8]),    \
            16, 0, 0);                                                                    \
    } while (0)

// One K-tile iteration (2 phases, 4 barriers). BUF/SBUF: 0/1. KT: next K-tile index
// (staged iff STG). Per-iter full drain: vmcnt(0) after phase-1 staging has had ~1
// K-tile in flight; lgkmcnt(0) before the final barrier (ds_reads of BUF drained
// before iter j+1 re-stages it).
#define K_ITER(BUF, SBUF, KT, STG)                                                        \
    {                                                                                     \
        const char* Ab = (const char*)&lds[BUF][0][0];                                    \
        const char* Bb = (const char*)&lds[BUF][1][0];                                    \
        bf16x8 b0 = __builtin_bit_cast(bf16x8, *(const u16x8*)(Bb + bRd[0]));             \
        bf16x8 b1 = __builtin_bit_cast(bf16x8, *(const u16x8*)(Bb + bRd[1]));             \
        bf16x8 b2 = __builtin_bit_cast(bf16x8, *(const u16x8*)(Bb + bRd[2]));             \
        bf16x8 b3 = __builtin_bit_cast(bf16x8, *(const u16x8*)(Bb + bRd[3]));             \
        bf16x8 a0 = __builtin_bit_cast(bf16x8, *(const u16x8*)(Ab + aRd[0]));             \
        bf16x8 a1 = __builtin_bit_cast(bf16x8, *(const u16x8*)(Ab + aRd[1]));             \
        bf16x8 a2 = __builtin_bit_cast(bf16x8, *(const u16x8*)(Ab + aRd[2]));             \
        bf16x8 a3 = __builtin_bit_cast(bf16x8, *(const u16x8*)(Ab + aRd[3]));             \
        if (STG) {                                                                        \
            STAGE_UNIT(SBUF, KT, 0, 1);                                                   \
            STAGE_UNIT(SBUF, KT, 1, 1);                                                   \
        }                                                                                 \
        asm volatile("" ::: "memory");                                                    \
        __builtin_amdgcn_s_barrier();                                                     \
        asm volatile("" ::: "memory");                                                    \
        __builtin_amdgcn_s_setprio(1);                                                    \
        acc[0][0] = __builtin_amdgcn_mfma_f32_16x16x32_bf16(a0, b0, acc[0][0], 0, 0, 0);  \
        acc[0][1] = __builtin_amdgcn_mfma_f32_16x16x32_bf16(a0, b1, acc[0][1], 0, 0, 0);  \
        acc[0][2] = __builtin_amdgcn_mfma_f32_16x16x32_bf16(a0, b2, acc[0][2], 0, 0, 0);  \
        acc[0][3] = __builtin_amdgcn_mfma_f32_16x16x32_bf16(a0, b3, acc[0][3], 0, 0, 0);  \
        acc[1][0] = __builtin_amdgcn_mfma_f32_16x16x32_bf16(a1, b0, acc[1][0], 0, 0, 0);  \
        acc[1][1] = __builtin_amdgcn_mfma_f32_16x16x32_bf16(a1, b1, acc[1][1], 0, 0, 0);  \
        acc[1][2] = __builtin_amdgcn_mfma_f32_16x16x32_bf16(a1, b2, acc[1][2], 0, 0, 0);  \
        acc[1][3] = __builtin_amdgcn_mfma_f32_16x16x32_bf16(a1, b3, acc[1][3], 0, 0, 0);  \
        acc[2][0] = __builtin_amdgcn_mfma_f32_16x16x32_bf16(a2, b0, acc[2][0], 0, 0, 0);  \
        acc[2][1] = __builtin_amdgcn_mfma_f32_16x16x32_bf16(a2, b1, acc[2][1], 0, 0, 0);  \
        acc[2][2] = __builtin_amdgcn_mfma_f32_16x16x32_bf16(a2, b2, acc[2][2], 0, 0, 0);  \
        acc[2][3] = __builtin_amdgcn_mfma_f32_16x16x32_bf16(a2, b3, acc[2][3], 0, 0, 0);  \
        acc[3][0] = __builtin_amdgcn_mfma_f32_16x16x32_bf16(a3, b0, acc[3][0], 0, 0, 0);  \
        acc[3][1] = __builtin_amdgcn_mfma_f32_16x16x32_bf16(a3, b1, acc[3][1], 0, 0, 0);  \
        acc[3][2] = __builtin_amdgcn_mfma_f32_16x16x32_bf16(a3, b2, acc[3][2], 0, 0, 0);  \
        acc[3][3] = __builtin_amdgcn_mfma_f32_16x16x32_bf16(a3, b3, acc[3][3], 0, 0, 0);  \
        __builtin_amdgcn_s_setprio(0);                                                    \
        asm volatile("" ::: "memory");                                                    \
        __builtin_amdgcn_s_barrier();                                                     \
        asm volatile("" ::: "memory");                                                    \
        bf16x8 a4 = __builtin_bit_cast(bf16x8, *(const u16x8*)(Ab + aRd[4]));             \
        bf16x8 a5 = __builtin_bit_cast(bf16x8, *(const u16x8*)(Ab + aRd[5]));             \
        bf16x8 a6 = __builtin_bit_cast(bf16x8, *(const u16x8*)(Ab + aRd[6]));             \
        bf16x8 a7 = __builtin_bit_cast(bf16x8, *(const u16x8*)(Ab + aRd[7]));             \
        if (STG) {                                                                        \
            STAGE_UNIT(SBUF, KT, 0, 0);                                                   \
            STAGE_UNIT(SBUF, KT, 1, 0);                                                   \
        }                                                                                 \
        asm volatile("" ::: "memory");                                                    \
        __builtin_amdgcn_s_barrier();                                                     \
        asm volatile("" ::: "memory");                                                    \
        __builtin_amdgcn_s_setprio(1);                                                    \
        acc[4][0] = __builtin_amdgcn_mfma_f32_16x16x32_bf16(a4, b0, acc[4][0], 0, 0, 0);  \
        acc[4][1] = __builtin_amdgcn_mfma_f32_16x16x32_bf16(a4, b1, acc[4][1], 0, 0, 0);  \
        acc[4][2] = __builtin_amdgcn_mfma_f32_16x16x32_bf16(a4, b2, acc[4][2], 0, 0, 0);  \
        acc[4][3] = __builtin_amdgcn_mfma_f32_16x16x32_bf16(a4, b3, acc[4][3], 0, 0, 0);  \
        acc[5][0] = __builtin_amdgcn_mfma_f32_16x16x32_bf16(a5, b0, acc[5][0], 0, 0, 0);  \
        acc[5][1] = __builtin_amdgcn_mfma_f32_16x16x32_bf16(a5, b1, acc[5][1], 0, 0, 0);  \
        acc[5][2] = __builtin_amdgcn_mfma_f32_16x16x32_bf16(a5, b2, acc[5][2], 0, 0, 0);  \
        acc[5][3] = __builtin_amdgcn_mfma_f32_16x16x32_bf16(a5, b3, acc[5][3], 0, 0, 0);  \
        acc[6][0] = __builtin_amdgcn_mfma_f32_16x16x32_bf16(a6, b0, acc[6][0], 0, 0, 0);  \
        acc[6][1] = __builtin_amdgcn_mfma_f32_16x16x32_bf16(a6, b1, acc[6][1], 0, 0, 0);  \
        acc[6][2] = __builtin_amdgcn_mfma_f32_16x16x32_bf16(a6, b2, acc[6][2], 0, 0, 0);  \
        acc[6][3] = __builtin_amdgcn_mfma_f32_16x16x32_bf16(a6, b3, acc[6][3], 0, 0, 0);  \
        acc[7][0] = __builtin_amdgcn_mfma_f32_16x16x32_bf16(a7, b0, acc[7][0], 0, 0, 0);  \
        acc[7][1] = __builtin_amdgcn_mfma_f32_16x16x32_bf16(a7, b1, acc[7][1], 0, 0, 0);  \
        acc[7][2] = __builtin_amdgcn_mfma_f32_16x16x32_bf16(a7, b2, acc[7][2], 0, 0, 0);  \
        acc[7][3] = __builtin_amdgcn_mfma_f32_16x16x32_bf16(a7, b3, acc[7][3], 0, 0, 0);  \
        __builtin_amdgcn_s_setprio(0);                                                    \
        if (STG) asm volatile("s_waitcnt vmcnt(0)" ::: "memory");                         \
        asm volatile("s_waitcnt lgkmcnt(0)" ::: "memory");                                \
        __builtin_amdgcn_s_barrier();                                                     \
        asm volatile("" ::: "memory");                                                    \
    }

    // ---- prologue: stage K-tile 0 into buf 0, full drain ----
    STAGE_UNIT(0, 0, 0, 1);
    STAGE_UNIT(0, 0, 1, 1);
    STAGE_UNIT(0, 0, 0, 0);
    STAGE_UNIT(0, 0, 1, 0);
    asm volatile("s_waitcnt vmcnt(0)" ::: "memory");
    __builtin_amdgcn_s_barrier();
    asm volatile("" ::: "memory");

    // ---- main loop: 128 K-tiles, ring-2, stage kt=j+1 during iter j ----
    for (int jj = 0; jj < 63; ++jj) {
        const int j = jj * 2;
        K_ITER(0, 1, j + 1, 1);
        K_ITER(1, 0, j + 2, 1);
    }
    K_ITER(0, 1, 127, 1);  // j=126: stage last K-tile
    K_ITER(1, 0, 0, 0);    // j=127: no stage; drains everything

    // ---- lora fold: stage mixbf/bwbf into buf 0 (safe: fully drained), one extra iter --
    STAGE_MIX(0, 1);
    STAGE_MIX(1, 1);
    STAGE_MIX(0, 0);
    STAGE_MIX(1, 0);
    asm volatile("s_waitcnt vmcnt(0)" ::: "memory");
    __builtin_amdgcn_s_barrier();
    asm volatile("" ::: "memory");
    K_ITER(0, 1, 0, 0);  // acc += (2*mixed) @ Bw^T  (K=32, cols 16-31 are zeros)
#undef K_ITER
#undef STAGE_MIX
#undef STAGE_UNIT

    // ---- epilogue: acc + bias only; C/D layout col=lane&15, row=(lane>>4)*4+j ----
    const int colq = lane & 15, rq = lane >> 4;
    float bcol[4];
    #pragma unroll
    for (int ni = 0; ni < 4; ++ni) bcol[ni] = bias[n0 + wcn * 64 + ni * 16 + colq];
    #pragma unroll
    for (int mi = 0; mi < 8; ++mi) {
        #pragma unroll
        for (int j = 0; j < 4; ++j) {
            const int row = m0 + wr * 128 + mi * 16 + rq * 4 + j;
            #pragma unroll
            for (int ni = 0; ni < 4; ++ni) {
                const int col = n0 + wcn * 64 + ni * 16 + colq;
                out[(size_t)row * O_DIM + col] = acc[mi][ni][j] + bcol[ni];
            }
        }
    }
}

extern "C" void kernel_launch(void* const* d_in, const int* in_sizes, int n_in,
                              void* d_out, int out_size, void* d_ws, size_t ws_size,
                              hipStream_t stream) {
    const float* x        = (const float*)d_in[0];
    const float* W_base   = (const float*)d_in[1];
    const float* b_base   = (const float*)d_in[2];
    const float* A_w      = (const float*)d_in[3];
    const float* B_w      = (const float*)d_in[4];
    const float* router_w = (const float*)d_in[5];
    const float* cores    = (const float*)d_in[6];
    float* out = (float*)d_out;

    char* ws = (char*)d_ws;
    unsigned short* xbf = (unsigned short*)ws;                                   // 64 MiB
    unsigned short* wbf = (unsigned short*)(ws + (size_t)M_DIM * D_DIM * 2);     // 32 MiB
    char* p = ws + (size_t)M_DIM * D_DIM * 2 + (size_t)O_DIM * D_DIM * 2;
    unsigned short* mixbf = (unsigned short*)p;                                  // 512 KiB
    unsigned short* bwbf  = (unsigned short*)(p + (size_t)M_DIM * 32 * 2);       // 256 KiB
    float* ypart = (float*)(p + (size_t)M_DIM * 32 * 2 + (size_t)O_DIM * 32 * 2);  // 6 MiB

    convert_bf16_kernel<<<2048, 256, 0, stream>>>(W_base, wbf, (O_DIM * D_DIM) / 4);
    partial_mixed_kernel<<<dim3(256, 8), 256, 0, stream>>>(x, A_w, router_w, xbf, ypart);
    fin_kernel<<<96, 128, 0, stream>>>(ypart, cores, B_w, mixbf, bwbf);
    gemm_kernel<<<512, 512, 0, stream>>>(xbf, wbf, b_base, mixbf, bwbf, out);
}

// Round 17
// 325.836 us; speedup vs baseline: 1.0643x; 1.0643x over previous
//
#include <hip/hip_runtime.h>
#include <stdint.h>

#define D_DIM 4096
#define O_DIM 4096
#define M_DIM 8192
#define BK 32
#define NKT 128  // D_DIM / BK

typedef __attribute__((ext_vector_type(4))) float f32x4;
typedef __attribute__((ext_vector_type(8))) __bf16 bf16x8;
typedef __attribute__((ext_vector_type(8))) unsigned short u16x8;

__device__ __forceinline__ unsigned short f32_to_bf16_bits(float f) {
    union { float f; uint32_t u; } v; v.f = f;
    return (unsigned short)((v.u + 0x7FFFu + ((v.u >> 16) & 1u)) >> 16);
}

__device__ __forceinline__ float dot4(f32x4 a, f32x4 b) {
    return fmaf(a.x, b.x, fmaf(a.y, b.y, fmaf(a.z, b.z, a.w * b.w)));
}

// swizzle involution on byte offsets within a 16 KiB [256 rows][64 B] tile:
// XOR bits 4-6 with bits 7-9. Conflict-free for the 16x16 fragment pattern
// (verified 0 conflicts rounds 3-15). Structural ledger: barrier-merge x (r4),
// 32x32 MFMA x (r14, bank conflicts), ring-2 occupancy x (r16, L2 thrash +
// exposed depth-1 drain). This ring-4 BK=32 form is the proven local optimum.
__device__ __forceinline__ int swz(int b) { return b ^ (((b >> 7) & 7) << 4); }

// ---------------- Kernel 1: f32 -> bf16 convert (W_base) ----------------
__global__ __launch_bounds__(256) void convert_bf16_kernel(const float* __restrict__ src,
                                                           unsigned short* __restrict__ dst,
                                                           int n4) {
    int stride = gridDim.x * blockDim.x;
    for (int i = blockIdx.x * blockDim.x + threadIdx.x; i < n4; i += stride) {
        f32x4 v = ((const f32x4*)src)[i];
        ushort4 o;
        o.x = f32_to_bf16_bits(v.x);
        o.y = f32_to_bf16_bits(v.y);
        o.z = f32_to_bf16_bits(v.z);
        o.w = f32_to_bf16_bits(v.w);
        ((ushort4*)dst)[i] = o;
    }
}

// ---------------- Kernel 2a: partial Y + fused x->bf16 convert (round-13, kept) ---------
__global__ __launch_bounds__(256) void partial_mixed_kernel(const float* __restrict__ x,
                                                            const float* __restrict__ A_w,
                                                            const float* __restrict__ router_w,
                                                            unsigned short* __restrict__ xbf,
                                                            float* __restrict__ ypart) {
    __shared__ __align__(16) float Xc[32][132];
    __shared__ __align__(16) float Wc[24][132];

    const int tid = threadIdx.x;
    const int t0 = blockIdx.x * 32;
    const int d0 = blockIdx.y * 512;

    const int slot = tid & 63;
    const int q = tid >> 6;
    const int tg4 = slot >> 3;
    const int og = slot & 7;

    float acc[4][3];
    #pragma unroll
    for (int ti = 0; ti < 4; ++ti)
        #pragma unroll
        for (int wi = 0; wi < 3; ++wi) acc[ti][wi] = 0.f;

    for (int sub = 0; sub < 4; ++sub) {
        const int dbase = d0 + sub * 128;
        __syncthreads();
        #pragma unroll
        for (int i = 0; i < 4; ++i) {
            int idx = i * 256 + tid;
            int t = idx >> 5, dq = idx & 31;
            f32x4 v = *(const f32x4*)&x[(size_t)(t0 + t) * D_DIM + dbase + dq * 4];
            *(f32x4*)&Xc[t][dq * 4] = v;
            ushort4 o;
            o.x = f32_to_bf16_bits(v.x);
            o.y = f32_to_bf16_bits(v.y);
            o.z = f32_to_bf16_bits(v.z);
            o.w = f32_to_bf16_bits(v.w);
            *(ushort4*)&xbf[(size_t)(t0 + t) * D_DIM + dbase + dq * 4] = o;
        }
        #pragma unroll
        for (int i = 0; i < 3; ++i) {
            int idx = i * 256 + tid;
            int r = idx >> 5, dq = idx & 31;
            const float* src = (r < 16) ? (A_w + (size_t)r * D_DIM)
                                        : (router_w + (size_t)(r - 16) * D_DIM);
            *(f32x4*)&Wc[r][dq * 4] = *(const f32x4*)&src[dbase + dq * 4];
        }
        __syncthreads();
        #pragma unroll
        for (int dqi = 0; dqi < 8; ++dqi) {
            const int dq = q * 8 + dqi;
            f32x4 w0 = *(const f32x4*)&Wc[og * 3 + 0][dq * 4];
            f32x4 w1 = *(const f32x4*)&Wc[og * 3 + 1][dq * 4];
            f32x4 w2 = *(const f32x4*)&Wc[og * 3 + 2][dq * 4];
            #pragma unroll
            for (int ti = 0; ti < 4; ++ti) {
                f32x4 xv = *(const f32x4*)&Xc[tg4 * 4 + ti][dq * 4];
                acc[ti][0] += dot4(xv, w0);
                acc[ti][1] += dot4(xv, w1);
                acc[ti][2] += dot4(xv, w2);
            }
        }
    }

    __syncthreads();
    float* red = &Xc[0][0];
    #pragma unroll
    for (int ti = 0; ti < 4; ++ti)
        #pragma unroll
        for (int wi = 0; wi < 3; ++wi)
            red[(slot * 4 + q) * 12 + ti * 3 + wi] = acc[ti][wi];
    __syncthreads();
    #pragma unroll
    for (int k = 0; k < 3; ++k) {
        const int flat = tid * 3 + k;
        const int t = flat / 24, j = flat % 24;
        const int s = ((t >> 2) << 3) | (j / 3);
        const int ti = t & 3, wi = j % 3;
        float v = 0.f;
        #pragma unroll
        for (int qq = 0; qq < 4; ++qq) v += red[(s * 4 + qq) * 12 + ti * 3 + wi];
        ypart[(((size_t)blockIdx.y * 256 + blockIdx.x) * 32 + t) * 24 + j] = v;
    }
}

// ---------------- Kernel 2b: finalize (blocks 0-63) + bwbf convert (blocks 64-95) --------
__global__ __launch_bounds__(128) void fin_kernel(const float* __restrict__ ypart,
                                                  const float* __restrict__ cores,
                                                  const float* __restrict__ Bw,
                                                  unsigned short* __restrict__ mixbf,
                                                  unsigned short* __restrict__ bwbf) {
    const int tid = threadIdx.x;

    if (blockIdx.x >= 64) {
        const int o = (blockIdx.x - 64) * 128 + tid;
        ushort4* dst = (ushort4*)&bwbf[(size_t)o * 32];
        #pragma unroll
        for (int g = 0; g < 4; ++g) {
            f32x4 v = *(const f32x4*)&Bw[(size_t)o * 16 + g * 4];
            ushort4 u;
            u.x = f32_to_bf16_bits(v.x);
            u.y = f32_to_bf16_bits(v.y);
            u.z = f32_to_bf16_bits(v.z);
            u.w = f32_to_bf16_bits(v.w);
            dst[g] = u;
        }
        const ushort4 z = {0, 0, 0, 0};
        #pragma unroll
        for (int g = 4; g < 8; ++g) dst[g] = z;
        return;
    }

    __shared__ __align__(16) float Cs[2048];
    #pragma unroll
    for (int i = 0; i < 4; ++i) {
        int idx = i * 128 + tid;
        ((f32x4*)Cs)[idx] = ((const f32x4*)cores)[idx];
    }
    __syncthreads();

    const int tok = blockIdx.x * 128 + tid;
    const int tile = tok >> 5, t = tok & 31;

    float y[24];
    #pragma unroll
    for (int j = 0; j < 24; ++j) y[j] = 0.f;
    for (int ds = 0; ds < 8; ++ds) {
        const float* src = ypart + (((size_t)ds * 256 + tile) * 32 + t) * 24;
        #pragma unroll
        for (int j = 0; j < 24; ++j) y[j] += src[j];
    }

    float mx = y[16];
    #pragma unroll
    for (int e = 1; e < 8; ++e) mx = fmaxf(mx, y[16 + e]);
    float p[8], psum = 0.f;
    #pragma unroll
    for (int e = 0; e < 8; ++e) { p[e] = __expf(y[16 + e] - mx); psum += p[e]; }
    const float inv = 1.0f / psum;

    float outq[16];
    #pragma unroll
    for (int q = 0; q < 16; ++q) outq[q] = 0.f;
    for (int e = 0; e < 8; ++e) {
        const float pe = p[e] * inv;
        #pragma unroll
        for (int r = 0; r < 16; ++r) {
            const float ar = y[r] * pe;
            #pragma unroll
            for (int q = 0; q < 16; ++q)
                outq[q] = fmaf(ar, Cs[(e * 16 + r) * 16 + q], outq[q]);
        }
    }
    ushort4* dst = (ushort4*)&mixbf[(size_t)tok * 32];
    #pragma unroll
    for (int g = 0; g < 4; ++g) {
        ushort4 u;
        u.x = f32_to_bf16_bits(2.0f * outq[g * 4 + 0]);
        u.y = f32_to_bf16_bits(2.0f * outq[g * 4 + 1]);
        u.z = f32_to_bf16_bits(2.0f * outq[g * 4 + 2]);
        u.w = f32_to_bf16_bits(2.0f * outq[g * 4 + 3]);
        dst[g] = u;
    }
    const ushort4 z = {0, 0, 0, 0};
    #pragma unroll
    for (int g = 4; g < 8; ++g) dst[g] = z;
}

// ---------------- Kernel 3: 256x256-tile deep-pipelined GEMM, lora folded into K-loop ---
// PROVEN round-10/13/15 version (243.6 us, MfmaUtil 51.5%, conflicts 0, post-timing OK).
// Ring-4 LDS (128 KiB), BK=32, counted vmcnt(8), race-fixed peeled tail, lora fold.
__global__ __launch_bounds__(512, 2) void gemm_kernel(const unsigned short* __restrict__ xbf,
                                                      const unsigned short* __restrict__ wbf,
                                                      const float* __restrict__ bias,
                                                      const unsigned short* __restrict__ mixbf,
                                                      const unsigned short* __restrict__ bwbf,
                                                      float* __restrict__ out) {
    __shared__ __align__(16) unsigned short lds[4][2][256 * 32];  // 128 KiB

    const int bid = blockIdx.x;
    const int xcd = bid & 7;
    const int lid = bid >> 3;                 // 0..63
    const int tm = (lid >> 4) * 8 + xcd;      // 0..31
    const int tn = lid & 15;                  // 0..15
    const int m0 = tm * 256, n0 = tn * 256;

    const int tid = threadIdx.x;
    const int wave = tid >> 6, lane = tid & 63;
    const int wr = wave >> 2, wcn = wave & 3;  // 2x4 wave grid

    int aoff[2], boff[2], mmoff[2], mboff[2];
    #pragma unroll
    for (int u = 0; u < 2; ++u) {
        int c = u * 512 + tid;
        int g = swz(c * 16);
        int grow = g >> 6, gc8 = (g >> 4) & 3;
        aoff[u] = (m0 + grow) * D_DIM + gc8 * 8;
        boff[u] = (n0 + grow) * D_DIM + gc8 * 8;
        mmoff[u] = (m0 + grow) * 32 + gc8 * 8;
        mboff[u] = (n0 + grow) * 32 + gc8 * 8;
    }

    const int tA = lane & 15, kq = lane >> 4;
    int aRd[8], bRd[4];
    #pragma unroll
    for (int mi = 0; mi < 8; ++mi)
        aRd[mi] = swz((wr * 128 + mi * 16 + tA) * 64 + kq * 16);
    #pragma unroll
    for (int ni = 0; ni < 4; ++ni)
        bRd[ni] = swz((wcn * 64 + ni * 16 + tA) * 64 + kq * 16);

    f32x4 acc[8][4];
    const f32x4 fz = {0.f, 0.f, 0.f, 0.f};
    #pragma unroll
    for (int mi = 0; mi < 8; ++mi)
        #pragma unroll
        for (int ni = 0; ni < 4; ++ni) acc[mi][ni] = fz;

#define STAGE_UNIT(sb, kt, u, isA)                                                        \
    do {                                                                                  \
        const unsigned short* gsrc =                                                      \
            (isA) ? (xbf + aoff[u] + (kt)*BK) : (wbf + boff[u] + (kt)*BK);                \
        __builtin_amdgcn_global_load_lds(                                                 \
            (const __attribute__((address_space(1))) void*)gsrc,                          \
            (__attribute__((address_space(3))) void*)(&lds[sb][(isA) ? 0 : 1]             \
                                                         [((u)*512 + wave * 64) * 8]),    \
            16, 0, 0);                                                                    \
    } while (0)

#define STAGE_MIX(u, isA)                                                                 \
    do {                                                                                  \
        const unsigned short* gsrc = (isA) ? (mixbf + mmoff[u]) : (bwbf + mboff[u]);      \
        __builtin_amdgcn_global_load_lds(                                                 \
            (const __attribute__((address_space(1))) void*)gsrc,                          \
            (__attribute__((address_space(3))) void*)(&lds[0][(isA) ? 0 : 1]              \
                                                         [((u)*512 + wave * 64) * 8]),    \
            16, 0, 0);                                                                    \
    } while (0)

// One K-tile iteration (2 phases, 4 barriers). STG: 0/1 literal (stage K-tile KT into
// SBUF). VMC: literal vmcnt count for the phase-1 counted wait.
#define K_ITER(BUF, SBUF, KT, STG, VMC)                                                   \
    {                                                                                     \
        const char* Ab = (const char*)&lds[BUF][0][0];                                    \
        const char* Bb = (const char*)&lds[BUF][1][0];                                    \
        bf16x8 b0 = __builtin_bit_cast(bf16x8, *(const u16x8*)(Bb + bRd[0]));             \
        bf16x8 b1 = __builtin_bit_cast(bf16x8, *(const u16x8*)(Bb + bRd[1]));             \
        bf16x8 b2 = __builtin_bit_cast(bf16x8, *(const u16x8*)(Bb + bRd[2]));             \
        bf16x8 b3 = __builtin_bit_cast(bf16x8, *(const u16x8*)(Bb + bRd[3]));             \
        bf16x8 a0 = __builtin_bit_cast(bf16x8, *(const u16x8*)(Ab + aRd[0]));             \
        bf16x8 a1 = __builtin_bit_cast(bf16x8, *(const u16x8*)(Ab + aRd[1]));             \
        bf16x8 a2 = __builtin_bit_cast(bf16x8, *(const u16x8*)(Ab + aRd[2]));             \
        bf16x8 a3 = __builtin_bit_cast(bf16x8, *(const u16x8*)(Ab + aRd[3]));             \
        if (STG) {                                                                        \
            STAGE_UNIT(SBUF, KT, 0, 1);                                                   \
            STAGE_UNIT(SBUF, KT, 1, 1);                                                   \
        }                                                                                 \
        asm volatile("" ::: "memory");                                                    \
        __builtin_amdgcn_s_barrier();                                                     \
        asm volatile("" ::: "memory");                                                    \
        __builtin_amdgcn_s_setprio(1);                                                    \
        acc[0][0] = __builtin_amdgcn_mfma_f32_16x16x32_bf16(a0, b0, acc[0][0], 0, 0, 0);  \
        acc[0][1] = __builtin_amdgcn_mfma_f32_16x16x32_bf16(a0, b1, acc[0][1], 0, 0, 0);  \
        acc[0][2] = __builtin_amdgcn_mfma_f32_16x16x32_bf16(a0, b2, acc[0][2], 0, 0, 0);  \
        acc[0][3] = __builtin_amdgcn_mfma_f32_16x16x32_bf16(a0, b3, acc[0][3], 0, 0, 0);  \
        acc[1][0] = __builtin_amdgcn_mfma_f32_16x16x32_bf16(a1, b0, acc[1][0], 0, 0, 0);  \
        acc[1][1] = __builtin_amdgcn_mfma_f32_16x16x32_bf16(a1, b1, acc[1][1], 0, 0, 0);  \
        acc[1][2] = __builtin_amdgcn_mfma_f32_16x16x32_bf16(a1, b2, acc[1][2], 0, 0, 0);  \
        acc[1][3] = __builtin_amdgcn_mfma_f32_16x16x32_bf16(a1, b3, acc[1][3], 0, 0, 0);  \
        acc[2][0] = __builtin_amdgcn_mfma_f32_16x16x32_bf16(a2, b0, acc[2][0], 0, 0, 0);  \
        acc[2][1] = __builtin_amdgcn_mfma_f32_16x16x32_bf16(a2, b1, acc[2][1], 0, 0, 0);  \
        acc[2][2] = __builtin_amdgcn_mfma_f32_16x16x32_bf16(a2, b2, acc[2][2], 0, 0, 0);  \
        acc[2][3] = __builtin_amdgcn_mfma_f32_16x16x32_bf16(a2, b3, acc[2][3], 0, 0, 0);  \
        acc[3][0] = __builtin_amdgcn_mfma_f32_16x16x32_bf16(a3, b0, acc[3][0], 0, 0, 0);  \
        acc[3][1] = __builtin_amdgcn_mfma_f32_16x16x32_bf16(a3, b1, acc[3][1], 0, 0, 0);  \
        acc[3][2] = __builtin_amdgcn_mfma_f32_16x16x32_bf16(a3, b2, acc[3][2], 0, 0, 0);  \
        acc[3][3] = __builtin_amdgcn_mfma_f32_16x16x32_bf16(a3, b3, acc[3][3], 0, 0, 0);  \
        __builtin_amdgcn_s_setprio(0);                                                    \
        asm volatile("" ::: "memory");                                                    \
        __builtin_amdgcn_s_barrier();                                                     \
        asm volatile("" ::: "memory");                                                    \
        bf16x8 a4 = __builtin_bit_cast(bf16x8, *(const u16x8*)(Ab + aRd[4]));             \
        bf16x8 a5 = __builtin_bit_cast(bf16x8, *(const u16x8*)(Ab + aRd[5]));             \
        bf16x8 a6 = __builtin_bit_cast(bf16x8, *(const u16x8*)(Ab + aRd[6]));             \
        bf16x8 a7 = __builtin_bit_cast(bf16x8, *(const u16x8*)(Ab + aRd[7]));             \
        if (STG) {                                                                        \
            STAGE_UNIT(SBUF, KT, 0, 0);                                                   \
            STAGE_UNIT(SBUF, KT, 1, 0);                                                   \
        }                                                                                 \
        asm volatile("s_waitcnt vmcnt(" #VMC ")" ::: "memory");                           \
        __builtin_amdgcn_s_barrier();                                                     \
        asm volatile("" ::: "memory");                                                    \
        __builtin_amdgcn_s_setprio(1);                                                    \
        acc[4][0] = __builtin_amdgcn_mfma_f32_16x16x32_bf16(a4, b0, acc[4][0], 0, 0, 0);  \
        acc[4][1] = __builtin_amdgcn_mfma_f32_16x16x32_bf16(a4, b1, acc[4][1], 0, 0, 0);  \
        acc[4][2] = __builtin_amdgcn_mfma_f32_16x16x32_bf16(a4, b2, acc[4][2], 0, 0, 0);  \
        acc[4][3] = __builtin_amdgcn_mfma_f32_16x16x32_bf16(a4, b3, acc[4][3], 0, 0, 0);  \
        acc[5][0] = __builtin_amdgcn_mfma_f32_16x16x32_bf16(a5, b0, acc[5][0], 0, 0, 0);  \
        acc[5][1] = __builtin_amdgcn_mfma_f32_16x16x32_bf16(a5, b1, acc[5][1], 0, 0, 0);  \
        acc[5][2] = __builtin_amdgcn_mfma_f32_16x16x32_bf16(a5, b2, acc[5][2], 0, 0, 0);  \
        acc[5][3] = __builtin_amdgcn_mfma_f32_16x16x32_bf16(a5, b3, acc[5][3], 0, 0, 0);  \
        acc[6][0] = __builtin_amdgcn_mfma_f32_16x16x32_bf16(a6, b0, acc[6][0], 0, 0, 0);  \
        acc[6][1] = __builtin_amdgcn_mfma_f32_16x16x32_bf16(a6, b1, acc[6][1], 0, 0, 0);  \
        acc[6][2] = __builtin_amdgcn_mfma_f32_16x16x32_bf16(a6, b2, acc[6][2], 0, 0, 0);  \
        acc[6][3] = __builtin_amdgcn_mfma_f32_16x16x32_bf16(a6, b3, acc[6][3], 0, 0, 0);  \
        acc[7][0] = __builtin_amdgcn_mfma_f32_16x16x32_bf16(a7, b0, acc[7][0], 0, 0, 0);  \
        acc[7][1] = __builtin_amdgcn_mfma_f32_16x16x32_bf16(a7, b1, acc[7][1], 0, 0, 0);  \
        acc[7][2] = __builtin_amdgcn_mfma_f32_16x16x32_bf16(a7, b2, acc[7][2], 0, 0, 0);  \
        acc[7][3] = __builtin_amdgcn_mfma_f32_16x16x32_bf16(a7, b3, acc[7][3], 0, 0, 0);  \
        __builtin_amdgcn_s_setprio(0);                                                    \
        asm volatile("s_waitcnt lgkmcnt(0)" ::: "memory");                                \
        __builtin_amdgcn_s_barrier();                                                     \
        asm volatile("" ::: "memory");                                                    \
    }

    // ---- prologue: stage K-tiles 0..2 (12 gload_lds/thread), wait all but K1,K2 ----
    #pragma unroll
    for (int kt = 0; kt < 3; ++kt) {
        STAGE_UNIT(kt, kt, 0, 1);
        STAGE_UNIT(kt, kt, 1, 1);
        STAGE_UNIT(kt, kt, 0, 0);
        STAGE_UNIT(kt, kt, 1, 0);
    }
    asm volatile("s_waitcnt vmcnt(8)" ::: "memory");
    __builtin_amdgcn_s_barrier();
    asm volatile("" ::: "memory");

    // ---- main loop: K-tiles 0..123 (staging always active, steady-state vmcnt(8)) ----
    for (int jj = 0; jj < 31; ++jj) {
        #pragma unroll
        for (int i = 0; i < 4; ++i) {
            const int j = jj * 4 + i;
            const int kt = j + 3;  // 3..126 < NKT: always stage
            K_ITER(i, (i + 3) & 3, kt, 1, 8);
        }
    }
    // ---- peeled tail: K-tiles 124..127 with explicit drains (race fix, round 6) ----
    K_ITER(0, 3, 127, 1, 8);  // j=124: stage kt=127; steady-state wait (kt=125 landed)
    K_ITER(1, 0, 0, 0, 4);    // j=125: no stage; drain to 4 -> kt=126 landed
    K_ITER(2, 0, 0, 0, 0);    // j=126: no stage; drain all -> kt=127 landed
    K_ITER(3, 0, 0, 0, 0);    // j=127: no stage; vmcnt(0) is a no-op

    // ---- lora fold: stage mixbf/bwbf into buf 0 (free since iter 124), one extra iter --
    STAGE_MIX(0, 1);
    STAGE_MIX(1, 1);
    STAGE_MIX(0, 0);
    STAGE_MIX(1, 0);
    asm volatile("s_waitcnt vmcnt(0)" ::: "memory");
    __builtin_amdgcn_s_barrier();
    asm volatile("" ::: "memory");
    K_ITER(0, 0, 0, 0, 0);  // acc += (2*mixed) @ Bw^T  (K=32, cols 16-31 are zeros)
#undef K_ITER
#undef STAGE_MIX
#undef STAGE_UNIT

    // ---- epilogue: acc + bias only; C/D layout col=lane&15, row=(lane>>4)*4+j ----
    const int colq = lane & 15, rq = lane >> 4;
    float bcol[4];
    #pragma unroll
    for (int ni = 0; ni < 4; ++ni) bcol[ni] = bias[n0 + wcn * 64 + ni * 16 + colq];
    #pragma unroll
    for (int mi = 0; mi < 8; ++mi) {
        #pragma unroll
        for (int j = 0; j < 4; ++j) {
            const int row = m0 + wr * 128 + mi * 16 + rq * 4 + j;
            #pragma unroll
            for (int ni = 0; ni < 4; ++ni) {
                const int col = n0 + wcn * 64 + ni * 16 + colq;
                out[(size_t)row * O_DIM + col] = acc[mi][ni][j] + bcol[ni];
            }
        }
    }
}

extern "C" void kernel_launch(void* const* d_in, const int* in_sizes, int n_in,
                              void* d_out, int out_size, void* d_ws, size_t ws_size,
                              hipStream_t stream) {
    const float* x        = (const float*)d_in[0];
    const float* W_base   = (const float*)d_in[1];
    const float* b_base   = (const float*)d_in[2];
    const float* A_w      = (const float*)d_in[3];
    const float* B_w      = (const float*)d_in[4];
    const float* router_w = (const float*)d_in[5];
    const float* cores    = (const float*)d_in[6];
    float* out = (float*)d_out;

    char* ws = (char*)d_ws;
    unsigned short* xbf = (unsigned short*)ws;                                   // 64 MiB
    unsigned short* wbf = (unsigned short*)(ws + (size_t)M_DIM * D_DIM * 2);     // 32 MiB
    char* p = ws + (size_t)M_DIM * D_DIM * 2 + (size_t)O_DIM * D_DIM * 2;
    unsigned short* mixbf = (unsigned short*)p;                                  // 512 KiB
    unsigned short* bwbf  = (unsigned short*)(p + (size_t)M_DIM * 32 * 2);       // 256 KiB
    float* ypart = (float*)(p + (size_t)M_DIM * 32 * 2 + (size_t)O_DIM * 32 * 2);  // 6 MiB

    convert_bf16_kernel<<<2048, 256, 0, stream>>>(W_base, wbf, (O_DIM * D_DIM) / 4);
    partial_mixed_kernel<<<dim3(256, 8), 256, 0, stream>>>(x, A_w, router_w, xbf, ypart);
    fin_kernel<<<96, 128, 0, stream>>>(ypart, cores, B_w, mixbf, bwbf);
    gemm_kernel<<<512, 512, 0, stream>>>(xbf, wbf, b_base, mixbf, bwbf, out);
}

// Round 18
// 323.518 us; speedup vs baseline: 1.0719x; 1.0072x over previous
//
#include <hip/hip_runtime.h>
#include <stdint.h>

#define D_DIM 4096
#define O_DIM 4096
#define M_DIM 8192
#define BK 32
#define NKT 128  // D_DIM / BK

typedef __attribute__((ext_vector_type(4))) float f32x4;
typedef __attribute__((ext_vector_type(8))) __bf16 bf16x8;
typedef __attribute__((ext_vector_type(8))) unsigned short u16x8;

__device__ __forceinline__ unsigned short f32_to_bf16_bits(float f) {
    union { float f; uint32_t u; } v; v.f = f;
    return (unsigned short)((v.u + 0x7FFFu + ((v.u >> 16) & 1u)) >> 16);
}

__device__ __forceinline__ float dot4(f32x4 a, f32x4 b) {
    return fmaf(a.x, b.x, fmaf(a.y, b.y, fmaf(a.z, b.z, a.w * b.w)));
}

// swizzle involution on byte offsets within a 16 KiB [256 rows][64 B] tile:
// XOR bits 4-6 with bits 7-9. Conflict-free for the 16x16 fragment pattern
// (verified 0 conflicts rounds 3-17).
__device__ __forceinline__ int swz(int b) { return b ^ (((b >> 7) & 7) << 4); }

// ---------------- Kernel 1: f32 -> bf16 convert (W_base) ----------------
__global__ __launch_bounds__(256) void convert_bf16_kernel(const float* __restrict__ src,
                                                           unsigned short* __restrict__ dst,
                                                           int n4) {
    int stride = gridDim.x * blockDim.x;
    for (int i = blockIdx.x * blockDim.x + threadIdx.x; i < n4; i += stride) {
        f32x4 v = ((const f32x4*)src)[i];
        ushort4 o;
        o.x = f32_to_bf16_bits(v.x);
        o.y = f32_to_bf16_bits(v.y);
        o.z = f32_to_bf16_bits(v.z);
        o.w = f32_to_bf16_bits(v.w);
        ((ushort4*)dst)[i] = o;
    }
}

// ---------------- Kernel 2a: partial Y + fused x->bf16 convert (v4) ----------------
// Round-18 fix of the v3 null: v3's compute read rows r = tg4*4+ti (lane stride 4,
// row pitch 132 floats -> bank = 4(r+dq) mod 32, stride-4 rows alias to 2 bank sets
// = 4-way conflict, cancelling the 0.44x traffic cut). v4 assigns each thread tokens
// tg4 + 8*ti: per-instruction lane rows are stride-1 -> banks all distinct ->
// conflict-free AND 0.44x traffic. Writeout inverts the new token mapping.
__global__ __launch_bounds__(256) void partial_mixed_kernel(const float* __restrict__ x,
                                                            const float* __restrict__ A_w,
                                                            const float* __restrict__ router_w,
                                                            unsigned short* __restrict__ xbf,
                                                            float* __restrict__ ypart) {
    __shared__ __align__(16) float Xc[32][132];
    __shared__ __align__(16) float Wc[24][132];

    const int tid = threadIdx.x;
    const int t0 = blockIdx.x * 32;
    const int d0 = blockIdx.y * 512;

    const int slot = tid & 63;   // 64 output slots
    const int q = tid >> 6;      // dq quarter 0..3
    const int tg4 = slot >> 3;   // token base: tokens tg4, tg4+8, tg4+16, tg4+24
    const int og = slot & 7;     // outs og*3 .. og*3+2

    float acc[4][3];
    #pragma unroll
    for (int ti = 0; ti < 4; ++ti)
        #pragma unroll
        for (int wi = 0; wi < 3; ++wi) acc[ti][wi] = 0.f;

    for (int sub = 0; sub < 4; ++sub) {
        const int dbase = d0 + sub * 128;
        __syncthreads();
        // stage Xc: 32x128 f32 = 1024 float4, 4 per thread; fused xbf convert
        #pragma unroll
        for (int i = 0; i < 4; ++i) {
            int idx = i * 256 + tid;
            int t = idx >> 5, dq = idx & 31;
            f32x4 v = *(const f32x4*)&x[(size_t)(t0 + t) * D_DIM + dbase + dq * 4];
            *(f32x4*)&Xc[t][dq * 4] = v;
            ushort4 o;
            o.x = f32_to_bf16_bits(v.x);
            o.y = f32_to_bf16_bits(v.y);
            o.z = f32_to_bf16_bits(v.z);
            o.w = f32_to_bf16_bits(v.w);
            *(ushort4*)&xbf[(size_t)(t0 + t) * D_DIM + dbase + dq * 4] = o;
        }
        // stage Wc: 24x128 f32 = 768 float4, 3 per thread
        #pragma unroll
        for (int i = 0; i < 3; ++i) {
            int idx = i * 256 + tid;
            int r = idx >> 5, dq = idx & 31;
            const float* src = (r < 16) ? (A_w + (size_t)r * D_DIM)
                                        : (router_w + (size_t)(r - 16) * D_DIM);
            *(f32x4*)&Wc[r][dq * 4] = *(const f32x4*)&src[dbase + dq * 4];
        }
        __syncthreads();
        // compute: this thread's dq-quarter; tokens tg4 + 8*ti (stride-8 per thread,
        // stride-1 across lanes -> conflict-free)
        #pragma unroll
        for (int dqi = 0; dqi < 8; ++dqi) {
            const int dq = q * 8 + dqi;
            f32x4 w0 = *(const f32x4*)&Wc[og * 3 + 0][dq * 4];
            f32x4 w1 = *(const f32x4*)&Wc[og * 3 + 1][dq * 4];
            f32x4 w2 = *(const f32x4*)&Wc[og * 3 + 2][dq * 4];
            #pragma unroll
            for (int ti = 0; ti < 4; ++ti) {
                f32x4 xv = *(const f32x4*)&Xc[tg4 + 8 * ti][dq * 4];
                acc[ti][0] += dot4(xv, w0);
                acc[ti][1] += dot4(xv, w1);
                acc[ti][2] += dot4(xv, w2);
            }
        }
    }

    // in-LDS reduce over the 4 dq-quarters (reuse Xc storage; all reads done)
    __syncthreads();
    float* red = &Xc[0][0];  // 64 slots x 4 q x 12 outs = 3072 floats
    #pragma unroll
    for (int ti = 0; ti < 4; ++ti)
        #pragma unroll
        for (int wi = 0; wi < 3; ++wi)
            red[(slot * 4 + q) * 12 + ti * 3 + wi] = acc[ti][wi];
    __syncthreads();
    // each thread writes 3 of the 768 outputs; token t lived in slot (t&7)*8 + j/3,
    // register slot ti = t>>3 (v4 mapping)
    #pragma unroll
    for (int k = 0; k < 3; ++k) {
        const int flat = tid * 3 + k;       // 0..767 = t*24 + j
        const int t = flat / 24, j = flat % 24;
        const int s = (t & 7) * 8 + (j / 3);
        const int ti = t >> 3, wi = j % 3;
        float v = 0.f;
        #pragma unroll
        for (int qq = 0; qq < 4; ++qq) v += red[(s * 4 + qq) * 12 + ti * 3 + wi];
        ypart[(((size_t)blockIdx.y * 256 + blockIdx.x) * 32 + t) * 24 + j] = v;
    }
}

// ---------------- Kernel 2b: finalize (blocks 0-63) + bwbf convert (blocks 64-95) --------
__global__ __launch_bounds__(128) void fin_kernel(const float* __restrict__ ypart,
                                                  const float* __restrict__ cores,
                                                  const float* __restrict__ Bw,
                                                  unsigned short* __restrict__ mixbf,
                                                  unsigned short* __restrict__ bwbf) {
    const int tid = threadIdx.x;

    if (blockIdx.x >= 64) {
        const int o = (blockIdx.x - 64) * 128 + tid;
        ushort4* dst = (ushort4*)&bwbf[(size_t)o * 32];
        #pragma unroll
        for (int g = 0; g < 4; ++g) {
            f32x4 v = *(const f32x4*)&Bw[(size_t)o * 16 + g * 4];
            ushort4 u;
            u.x = f32_to_bf16_bits(v.x);
            u.y = f32_to_bf16_bits(v.y);
            u.z = f32_to_bf16_bits(v.z);
            u.w = f32_to_bf16_bits(v.w);
            dst[g] = u;
        }
        const ushort4 z = {0, 0, 0, 0};
        #pragma unroll
        for (int g = 4; g < 8; ++g) dst[g] = z;
        return;
    }

    __shared__ __align__(16) float Cs[2048];
    #pragma unroll
    for (int i = 0; i < 4; ++i) {
        int idx = i * 128 + tid;
        ((f32x4*)Cs)[idx] = ((const f32x4*)cores)[idx];
    }
    __syncthreads();

    const int tok = blockIdx.x * 128 + tid;
    const int tile = tok >> 5, t = tok & 31;

    float y[24];
    #pragma unroll
    for (int j = 0; j < 24; ++j) y[j] = 0.f;
    for (int ds = 0; ds < 8; ++ds) {
        const float* src = ypart + (((size_t)ds * 256 + tile) * 32 + t) * 24;
        #pragma unroll
        for (int j = 0; j < 24; ++j) y[j] += src[j];
    }

    float mx = y[16];
    #pragma unroll
    for (int e = 1; e < 8; ++e) mx = fmaxf(mx, y[16 + e]);
    float p[8], psum = 0.f;
    #pragma unroll
    for (int e = 0; e < 8; ++e) { p[e] = __expf(y[16 + e] - mx); psum += p[e]; }
    const float inv = 1.0f / psum;

    float outq[16];
    #pragma unroll
    for (int q = 0; q < 16; ++q) outq[q] = 0.f;
    for (int e = 0; e < 8; ++e) {
        const float pe = p[e] * inv;
        #pragma unroll
        for (int r = 0; r < 16; ++r) {
            const float ar = y[r] * pe;
            #pragma unroll
            for (int q = 0; q < 16; ++q)
                outq[q] = fmaf(ar, Cs[(e * 16 + r) * 16 + q], outq[q]);
        }
    }
    ushort4* dst = (ushort4*)&mixbf[(size_t)tok * 32];
    #pragma unroll
    for (int g = 0; g < 4; ++g) {
        ushort4 u;
        u.x = f32_to_bf16_bits(2.0f * outq[g * 4 + 0]);
        u.y = f32_to_bf16_bits(2.0f * outq[g * 4 + 1]);
        u.z = f32_to_bf16_bits(2.0f * outq[g * 4 + 2]);
        u.w = f32_to_bf16_bits(2.0f * outq[g * 4 + 3]);
        dst[g] = u;
    }
    const ushort4 z = {0, 0, 0, 0};
    #pragma unroll
    for (int g = 4; g < 8; ++g) dst[g] = z;
}

// ---------------- Kernel 3: 256x256-tile deep-pipelined GEMM, lora folded into K-loop ---
// FROZEN round-10/13/15/17 version (242.5 us, MfmaUtil 52.4%, conflicts 0).
__global__ __launch_bounds__(512, 2) void gemm_kernel(const unsigned short* __restrict__ xbf,
                                                      const unsigned short* __restrict__ wbf,
                                                      const float* __restrict__ bias,
                                                      const unsigned short* __restrict__ mixbf,
                                                      const unsigned short* __restrict__ bwbf,
                                                      float* __restrict__ out) {
    __shared__ __align__(16) unsigned short lds[4][2][256 * 32];  // 128 KiB

    const int bid = blockIdx.x;
    const int xcd = bid & 7;
    const int lid = bid >> 3;                 // 0..63
    const int tm = (lid >> 4) * 8 + xcd;      // 0..31
    const int tn = lid & 15;                  // 0..15
    const int m0 = tm * 256, n0 = tn * 256;

    const int tid = threadIdx.x;
    const int wave = tid >> 6, lane = tid & 63;
    const int wr = wave >> 2, wcn = wave & 3;  // 2x4 wave grid

    int aoff[2], boff[2], mmoff[2], mboff[2];
    #pragma unroll
    for (int u = 0; u < 2; ++u) {
        int c = u * 512 + tid;
        int g = swz(c * 16);
        int grow = g >> 6, gc8 = (g >> 4) & 3;
        aoff[u] = (m0 + grow) * D_DIM + gc8 * 8;
        boff[u] = (n0 + grow) * D_DIM + gc8 * 8;
        mmoff[u] = (m0 + grow) * 32 + gc8 * 8;
        mboff[u] = (n0 + grow) * 32 + gc8 * 8;
    }

    const int tA = lane & 15, kq = lane >> 4;
    int aRd[8], bRd[4];
    #pragma unroll
    for (int mi = 0; mi < 8; ++mi)
        aRd[mi] = swz((wr * 128 + mi * 16 + tA) * 64 + kq * 16);
    #pragma unroll
    for (int ni = 0; ni < 4; ++ni)
        bRd[ni] = swz((wcn * 64 + ni * 16 + tA) * 64 + kq * 16);

    f32x4 acc[8][4];
    const f32x4 fz = {0.f, 0.f, 0.f, 0.f};
    #pragma unroll
    for (int mi = 0; mi < 8; ++mi)
        #pragma unroll
        for (int ni = 0; ni < 4; ++ni) acc[mi][ni] = fz;

#define STAGE_UNIT(sb, kt, u, isA)                                                        \
    do {                                                                                  \
        const unsigned short* gsrc =                                                      \
            (isA) ? (xbf + aoff[u] + (kt)*BK) : (wbf + boff[u] + (kt)*BK);                \
        __builtin_amdgcn_global_load_lds(                                                 \
            (const __attribute__((address_space(1))) void*)gsrc,                          \
            (__attribute__((address_space(3))) void*)(&lds[sb][(isA) ? 0 : 1]             \
                                                         [((u)*512 + wave * 64) * 8]),    \
            16, 0, 0);                                                                    \
    } while (0)

#define STAGE_MIX(u, isA)                                                                 \
    do {                                                                                  \
        const unsigned short* gsrc = (isA) ? (mixbf + mmoff[u]) : (bwbf + mboff[u]);      \
        __builtin_amdgcn_global_load_lds(                                                 \
            (const __attribute__((address_space(1))) void*)gsrc,                          \
            (__attribute__((address_space(3))) void*)(&lds[0][(isA) ? 0 : 1]              \
                                                         [((u)*512 + wave * 64) * 8]),    \
            16, 0, 0);                                                                    \
    } while (0)

// One K-tile iteration (2 phases, 4 barriers). STG: 0/1 literal (stage K-tile KT into
// SBUF). VMC: literal vmcnt count for the phase-1 counted wait.
#define K_ITER(BUF, SBUF, KT, STG, VMC)                                                   \
    {                                                                                     \
        const char* Ab = (const char*)&lds[BUF][0][0];                                    \
        const char* Bb = (const char*)&lds[BUF][1][0];                                    \
        bf16x8 b0 = __builtin_bit_cast(bf16x8, *(const u16x8*)(Bb + bRd[0]));             \
        bf16x8 b1 = __builtin_bit_cast(bf16x8, *(const u16x8*)(Bb + bRd[1]));             \
        bf16x8 b2 = __builtin_bit_cast(bf16x8, *(const u16x8*)(Bb + bRd[2]));             \
        bf16x8 b3 = __builtin_bit_cast(bf16x8, *(const u16x8*)(Bb + bRd[3]));             \
        bf16x8 a0 = __builtin_bit_cast(bf16x8, *(const u16x8*)(Ab + aRd[0]));             \
        bf16x8 a1 = __builtin_bit_cast(bf16x8, *(const u16x8*)(Ab + aRd[1]));             \
        bf16x8 a2 = __builtin_bit_cast(bf16x8, *(const u16x8*)(Ab + aRd[2]));             \
        bf16x8 a3 = __builtin_bit_cast(bf16x8, *(const u16x8*)(Ab + aRd[3]));             \
        if (STG) {                                                                        \
            STAGE_UNIT(SBUF, KT, 0, 1);                                                   \
            STAGE_UNIT(SBUF, KT, 1, 1);                                                   \
        }                                                                                 \
        asm volatile("" ::: "memory");                                                    \
        __builtin_amdgcn_s_barrier();                                                     \
        asm volatile("" ::: "memory");                                                    \
        __builtin_amdgcn_s_setprio(1);                                                    \
        acc[0][0] = __builtin_amdgcn_mfma_f32_16x16x32_bf16(a0, b0, acc[0][0], 0, 0, 0);  \
        acc[0][1] = __builtin_amdgcn_mfma_f32_16x16x32_bf16(a0, b1, acc[0][1], 0, 0, 0);  \
        acc[0][2] = __builtin_amdgcn_mfma_f32_16x16x32_bf16(a0, b2, acc[0][2], 0, 0, 0);  \
        acc[0][3] = __builtin_amdgcn_mfma_f32_16x16x32_bf16(a0, b3, acc[0][3], 0, 0, 0);  \
        acc[1][0] = __builtin_amdgcn_mfma_f32_16x16x32_bf16(a1, b0, acc[1][0], 0, 0, 0);  \
        acc[1][1] = __builtin_amdgcn_mfma_f32_16x16x32_bf16(a1, b1, acc[1][1], 0, 0, 0);  \
        acc[1][2] = __builtin_amdgcn_mfma_f32_16x16x32_bf16(a1, b2, acc[1][2], 0, 0, 0);  \
        acc[1][3] = __builtin_amdgcn_mfma_f32_16x16x32_bf16(a1, b3, acc[1][3], 0, 0, 0);  \
        acc[2][0] = __builtin_amdgcn_mfma_f32_16x16x32_bf16(a2, b0, acc[2][0], 0, 0, 0);  \
        acc[2][1] = __builtin_amdgcn_mfma_f32_16x16x32_bf16(a2, b1, acc[2][1], 0, 0, 0);  \
        acc[2][2] = __builtin_amdgcn_mfma_f32_16x16x32_bf16(a2, b2, acc[2][2], 0, 0, 0);  \
        acc[2][3] = __builtin_amdgcn_mfma_f32_16x16x32_bf16(a2, b3, acc[2][3], 0, 0, 0);  \
        acc[3][0] = __builtin_amdgcn_mfma_f32_16x16x32_bf16(a3, b0, acc[3][0], 0, 0, 0);  \
        acc[3][1] = __builtin_amdgcn_mfma_f32_16x16x32_bf16(a3, b1, acc[3][1], 0, 0, 0);  \
        acc[3][2] = __builtin_amdgcn_mfma_f32_16x16x32_bf16(a3, b2, acc[3][2], 0, 0, 0);  \
        acc[3][3] = __builtin_amdgcn_mfma_f32_16x16x32_bf16(a3, b3, acc[3][3], 0, 0, 0);  \
        __builtin_amdgcn_s_setprio(0);                                                    \
        asm volatile("" ::: "memory");                                                    \
        __builtin_amdgcn_s_barrier();                                                     \
        asm volatile("" ::: "memory");                                                    \
        bf16x8 a4 = __builtin_bit_cast(bf16x8, *(const u16x8*)(Ab + aRd[4]));             \
        bf16x8 a5 = __builtin_bit_cast(bf16x8, *(const u16x8*)(Ab + aRd[5]));             \
        bf16x8 a6 = __builtin_bit_cast(bf16x8, *(const u16x8*)(Ab + aRd[6]));             \
        bf16x8 a7 = __builtin_bit_cast(bf16x8, *(const u16x8*)(Ab + aRd[7]));             \
        if (STG) {                                                                        \
            STAGE_UNIT(SBUF, KT, 0, 0);                                                   \
            STAGE_UNIT(SBUF, KT, 1, 0);                                                   \
        }                                                                                 \
        asm volatile("s_waitcnt vmcnt(" #VMC ")" ::: "memory");                           \
        __builtin_amdgcn_s_barrier();                                                     \
        asm volatile("" ::: "memory");                                                    \
        __builtin_amdgcn_s_setprio(1);                                                    \
        acc[4][0] = __builtin_amdgcn_mfma_f32_16x16x32_bf16(a4, b0, acc[4][0], 0, 0, 0);  \
        acc[4][1] = __builtin_amdgcn_mfma_f32_16x16x32_bf16(a4, b1, acc[4][1], 0, 0, 0);  \
        acc[4][2] = __builtin_amdgcn_mfma_f32_16x16x32_bf16(a4, b2, acc[4][2], 0, 0, 0);  \
        acc[4][3] = __builtin_amdgcn_mfma_f32_16x16x32_bf16(a4, b3, acc[4][3], 0, 0, 0);  \
        acc[5][0] = __builtin_amdgcn_mfma_f32_16x16x32_bf16(a5, b0, acc[5][0], 0, 0, 0);  \
        acc[5][1] = __builtin_amdgcn_mfma_f32_16x16x32_bf16(a5, b1, acc[5][1], 0, 0, 0);  \
        acc[5][2] = __builtin_amdgcn_mfma_f32_16x16x32_bf16(a5, b2, acc[5][2], 0, 0, 0);  \
        acc[5][3] = __builtin_amdgcn_mfma_f32_16x16x32_bf16(a5, b3, acc[5][3], 0, 0, 0);  \
        acc[6][0] = __builtin_amdgcn_mfma_f32_16x16x32_bf16(a6, b0, acc[6][0], 0, 0, 0);  \
        acc[6][1] = __builtin_amdgcn_mfma_f32_16x16x32_bf16(a6, b1, acc[6][1], 0, 0, 0);  \
        acc[6][2] = __builtin_amdgcn_mfma_f32_16x16x32_bf16(a6, b2, acc[6][2], 0, 0, 0);  \
        acc[6][3] = __builtin_amdgcn_mfma_f32_16x16x32_bf16(a6, b3, acc[6][3], 0, 0, 0);  \
        acc[7][0] = __builtin_amdgcn_mfma_f32_16x16x32_bf16(a7, b0, acc[7][0], 0, 0, 0);  \
        acc[7][1] = __builtin_amdgcn_mfma_f32_16x16x32_bf16(a7, b1, acc[7][1], 0, 0, 0);  \
        acc[7][2] = __builtin_amdgcn_mfma_f32_16x16x32_bf16(a7, b2, acc[7][2], 0, 0, 0);  \
        acc[7][3] = __builtin_amdgcn_mfma_f32_16x16x32_bf16(a7, b3, acc[7][3], 0, 0, 0);  \
        __builtin_amdgcn_s_setprio(0);                                                    \
        asm volatile("s_waitcnt lgkmcnt(0)" ::: "memory");                                \
        __builtin_amdgcn_s_barrier();                                                     \
        asm volatile("" ::: "memory");                                                    \
    }

    // ---- prologue: stage K-tiles 0..2 (12 gload_lds/thread), wait all but K1,K2 ----
    #pragma unroll
    for (int kt = 0; kt < 3; ++kt) {
        STAGE_UNIT(kt, kt, 0, 1);
        STAGE_UNIT(kt, kt, 1, 1);
        STAGE_UNIT(kt, kt, 0, 0);
        STAGE_UNIT(kt, kt, 1, 0);
    }
    asm volatile("s_waitcnt vmcnt(8)" ::: "memory");
    __builtin_amdgcn_s_barrier();
    asm volatile("" ::: "memory");

    // ---- main loop: K-tiles 0..123 (staging always active, steady-state vmcnt(8)) ----
    for (int jj = 0; jj < 31; ++jj) {
        #pragma unroll
        for (int i = 0; i < 4; ++i) {
            const int j = jj * 4 + i;
            const int kt = j + 3;  // 3..126 < NKT: always stage
            K_ITER(i, (i + 3) & 3, kt, 1, 8);
        }
    }
    // ---- peeled tail: K-tiles 124..127 with explicit drains (race fix, round 6) ----
    K_ITER(0, 3, 127, 1, 8);  // j=124: stage kt=127; steady-state wait (kt=125 landed)
    K_ITER(1, 0, 0, 0, 4);    // j=125: no stage; drain to 4 -> kt=126 landed
    K_ITER(2, 0, 0, 0, 0);    // j=126: no stage; drain all -> kt=127 landed
    K_ITER(3, 0, 0, 0, 0);    // j=127: no stage; vmcnt(0) is a no-op

    // ---- lora fold: stage mixbf/bwbf into buf 0 (free since iter 124), one extra iter --
    STAGE_MIX(0, 1);
    STAGE_MIX(1, 1);
    STAGE_MIX(0, 0);
    STAGE_MIX(1, 0);
    asm volatile("s_waitcnt vmcnt(0)" ::: "memory");
    __builtin_amdgcn_s_barrier();
    asm volatile("" ::: "memory");
    K_ITER(0, 0, 0, 0, 0);  // acc += (2*mixed) @ Bw^T  (K=32, cols 16-31 are zeros)
#undef K_ITER
#undef STAGE_MIX
#undef STAGE_UNIT

    // ---- epilogue: acc + bias only; C/D layout col=lane&15, row=(lane>>4)*4+j ----
    const int colq = lane & 15, rq = lane >> 4;
    float bcol[4];
    #pragma unroll
    for (int ni = 0; ni < 4; ++ni) bcol[ni] = bias[n0 + wcn * 64 + ni * 16 + colq];
    #pragma unroll
    for (int mi = 0; mi < 8; ++mi) {
        #pragma unroll
        for (int j = 0; j < 4; ++j) {
            const int row = m0 + wr * 128 + mi * 16 + rq * 4 + j;
            #pragma unroll
            for (int ni = 0; ni < 4; ++ni) {
                const int col = n0 + wcn * 64 + ni * 16 + colq;
                out[(size_t)row * O_DIM + col] = acc[mi][ni][j] + bcol[ni];
            }
        }
    }
}

extern "C" void kernel_launch(void* const* d_in, const int* in_sizes, int n_in,
                              void* d_out, int out_size, void* d_ws, size_t ws_size,
                              hipStream_t stream) {
    const float* x        = (const float*)d_in[0];
    const float* W_base   = (const float*)d_in[1];
    const float* b_base   = (const float*)d_in[2];
    const float* A_w      = (const float*)d_in[3];
    const float* B_w      = (const float*)d_in[4];
    const float* router_w = (const float*)d_in[5];
    const float* cores    = (const float*)d_in[6];
    float* out = (float*)d_out;

    char* ws = (char*)d_ws;
    unsigned short* xbf = (unsigned short*)ws;                                   // 64 MiB
    unsigned short* wbf = (unsigned short*)(ws + (size_t)M_DIM * D_DIM * 2);     // 32 MiB
    char* p = ws + (size_t)M_DIM * D_DIM * 2 + (size_t)O_DIM * D_DIM * 2;
    unsigned short* mixbf = (unsigned short*)p;                                  // 512 KiB
    unsigned short* bwbf  = (unsigned short*)(p + (size_t)M_DIM * 32 * 2);       // 256 KiB
    float* ypart = (float*)(p + (size_t)M_DIM * 32 * 2 + (size_t)O_DIM * 32 * 2);  // 6 MiB

    convert_bf16_kernel<<<2048, 256, 0, stream>>>(W_base, wbf, (O_DIM * D_DIM) / 4);
    partial_mixed_kernel<<<dim3(256, 8), 256, 0, stream>>>(x, A_w, router_w, xbf, ypart);
    fin_kernel<<<96, 128, 0, stream>>>(ypart, cores, B_w, mixbf, bwbf);
    gemm_kernel<<<512, 512, 0, stream>>>(xbf, wbf, b_base, mixbf, bwbf, out);
}